// Round 15
// baseline (742.952 us; speedup 1.0000x reference)
//
#include <hip/hip_runtime.h>
#include <hip/hip_fp16.h>
#include <cstdint>

#define HD    128
#define OUTD  10
#define NG    512
#define KSTEPS 10

typedef unsigned short ushort_t;
typedef unsigned int   uint_t;
typedef unsigned char  uchar_t;
typedef float vf2 __attribute__((ext_vector_type(2)));
typedef short bf16x8 __attribute__((ext_vector_type(8)));   // MFMA A/B frag (8 bf16)
typedef float f32x4  __attribute__((ext_vector_type(4)));   // MFMA C/D frag

// bf16 helpers (x/h stored as bf16: REQUIRED — propagated values reach ~1e10,
// f16 overflows at 65504 (R9 failure). f32 accumulate everywhere.)
__device__ __forceinline__ float bf_lo(uint_t u) { return __uint_as_float(u << 16); }
__device__ __forceinline__ float bf_hi(uint_t u) { return __uint_as_float(u & 0xFFFF0000u); }
__device__ __forceinline__ uint_t f2bf_rne(float f) {          // 16-bit result
    uint_t u = __float_as_uint(f);
    return (u + 0x7FFFu + ((u >> 16) & 1u)) >> 16;
}
__device__ __forceinline__ uint_t pack_bf2(float lo, float hi) {
    return f2bf_rne(lo) | (f2bf_rne(hi) << 16);
}

// packed f32 FMA (CDNA VOP3P): d = a*b + c on both lanes of the pair.
__device__ __forceinline__ vf2 pk_fma(vf2 a, vf2 b, vf2 c) {
    vf2 d;
    asm("v_pk_fma_f32 %0, %1, %2, %3" : "=v"(d) : "v"(a), "v"(b), "v"(c));
    return d;
}

// ---------------------------------------------------------------------------
// 1) Collapse the two linear layers: Wc = W1@W2, bc = b1@W2 + b2
// ---------------------------------------------------------------------------
__global__ void wc_kernel(const float* __restrict__ W1, const float* __restrict__ b1,
                          const float* __restrict__ W2, const float* __restrict__ b2,
                          float* __restrict__ Wc, float* __restrict__ bc) {
    int idx = blockIdx.x * 256 + threadIdx.x;      // 0..16383
    int d = idx >> 7, j = idx & 127;
    float s = 0.f;
    for (int t = 0; t < HD; t++) s += W1[d * HD + t] * W2[t * HD + j];
    Wc[idx] = s;
    if (idx < HD) {
        float sb = b2[idx];
        for (int t = 0; t < HD; t++) sb += b1[t] * W2[t * HD + idx];
        bc[idx] = sb;
    }
}

// ---------------------------------------------------------------------------
// 2) h[n][j] = sum_d feat[d][n]*Wc[d][j] + bc[j] -> bf16 [N][128]
//    MFMA version (R14 lesson: VALU tiles are pinned at 43-50 us by the
//    LDS-traffic / occupancy bind; mfma_16x16x32_bf16 consumes 8 bf16 per
//    16B LDS read -> LDS time ~4 us, leaving the 25.6 MB feat read as floor).
//    64 nodes x 128 j per block; 4 waves, each owns a 16-node stripe.
//    Fragment mapping (m89/m91-verified): A row=lane&15, k=(lane>>4)*8+i;
//    B col=lane&15, same k; D col=lane&15, row=(lane>>4)*4+reg.
//    LDS rows padded to 136 ushorts (272 B) -> residual 2-way conflicts only.
//    bf16 input rounding (~0.4%) is same order as the h bf16 rounding
//    already applied; threshold ~3%.
// ---------------------------------------------------------------------------
#define FNT 64                  // nodes per block
__global__ void __launch_bounds__(256) feat_kernel(
        const float* __restrict__ feat, const float* __restrict__ Wc,
        const float* __restrict__ bc, ushort_t* __restrict__ h, int N) {
    __shared__ ushort_t As[FNT][136];         // [node][d] bf16, 17.4 KB
    __shared__ ushort_t Bt[HD][136];          // [j][d]    bf16, 34.8 KB
    int t = threadIdx.x;
    int nb0 = blockIdx.x * FNT;
    int wid = t >> 6, lane = t & 63;

    // stage A: feat[d][nb0+n] -> bf16 As[n][d]   (64 n x 128 d)
    #pragma unroll
    for (int k = 0; k < (FNT * HD) / 256; k++) {      // 32 iters
        int l = k * 256 + t;
        int n = l & 63, d = l >> 6;
        int nn = nb0 + n;
        float v = (nn < N) ? feat[(size_t)d * N + nn] : 0.f;
        As[n][d] = (ushort_t)f2bf_rne(v);
    }
    // stage B: Wc[d][j] -> bf16 Bt[j][d]          (128 j x 128 d)
    #pragma unroll
    for (int k = 0; k < (HD * HD) / 256; k++) {       // 64 iters
        int l = k * 256 + t;
        int j = l & 127, d = l >> 7;
        Bt[j][d] = (ushort_t)f2bf_rne(Wc[d * HD + j]);
    }
    __syncthreads();

    int arow = wid * 16 + (lane & 15);        // node row within block
    int koff = (lane >> 4) * 8;               // k-offset within 32-chunk

    f32x4 acc[8];
    #pragma unroll
    for (int jt = 0; jt < 8; jt++) acc[jt] = (f32x4)0.f;

    #pragma unroll
    for (int ks = 0; ks < 4; ks++) {          // K = 128 in 4 chunks of 32
        bf16x8 av = *(const bf16x8*)&As[arow][ks * 32 + koff];
        #pragma unroll
        for (int jt = 0; jt < 8; jt++) {
            bf16x8 bv = *(const bf16x8*)&Bt[jt * 16 + (lane & 15)][ks * 32 + koff];
            acc[jt] = __builtin_amdgcn_mfma_f32_16x16x32_bf16(av, bv, acc[jt], 0, 0, 0);
        }
    }

    // epilogue: D col=lane&15 (j within tile), row=(lane>>4)*4+r (node)
    int drow = wid * 16 + (lane >> 4) * 4;    // node row base for this lane
    #pragma unroll
    for (int jt = 0; jt < 8; jt++) {
        int j = jt * 16 + (lane & 15);
        float bb = bc[j];
        #pragma unroll
        for (int r = 0; r < 4; r++) {
            int n = nb0 + drow + r;
            if (n < N) h[(size_t)n * HD + j] = (ushort_t)f2bf_rne(acc[jt][r] + bb);
        }
    }
}

// ---------------------------------------------------------------------------
// 3) CSR build via two-level bucket sort (NO global per-node atomics).
// ---------------------------------------------------------------------------

// S1: global bucket sizes (LDS hist, then one atomic per nonzero bucket/block)
__global__ void __launch_bounds__(256) bcount_kernel(
        const int* __restrict__ ei, int* __restrict__ gbhist, int E, int chunk) {
    __shared__ int lh[256];
    int b = blockIdx.x, t = threadIdx.x;
    lh[t] = 0;
    __syncthreads();
    int lo = b * chunk, hi = min(E, lo + chunk);
    for (int i = lo + t; i < hi; i += 256) atomicAdd(&lh[ei[E + i] >> 8], 1);
    __syncthreads();
    if (lh[t]) atomicAdd(&gbhist[t], lh[t]);
}

// S2: exclusive scan of bucket sizes -> bucket_base[0..NBK], bcursor init
__global__ void bscan_kernel(const int* __restrict__ gbhist, int* __restrict__ bucket_base,
                             int* __restrict__ bcursor, int NBK, int E) {
    __shared__ int sm[256];
    int t = threadIdx.x;
    int v = (t < NBK) ? gbhist[t] : 0;
    sm[t] = v;
    __syncthreads();
    for (int off = 1; off < 256; off <<= 1) {
        int u = (t >= off) ? sm[t - off] : 0;
        __syncthreads();
        sm[t] += u;
        __syncthreads();
    }
    int excl = sm[t] - v;
    if (t < NBK) { bucket_base[t] = excl; bcursor[t] = excl; }
    if (t == 0) bucket_base[NBK] = E;
}

// S3: scatter edges into bucket-ordered intermediate (rec + low-byte of dst).
// Record: (src << 16) | bf16(weight) — bf16 w decodes with ONE shift in prop.
__global__ void __launch_bounds__(256) bscatter_kernel(
        const int* __restrict__ ei, const float* __restrict__ ewt,
        int* __restrict__ bcursor, uint_t* __restrict__ rec_tmp,
        uchar_t* __restrict__ dlo_tmp, int E, int chunk) {
    __shared__ int lh[256];
    __shared__ int lcur[256];
    int b = blockIdx.x, t = threadIdx.x;
    lh[t] = 0;
    __syncthreads();
    int lo = b * chunk, hi = min(E, lo + chunk);
    for (int i = lo + t; i < hi; i += 256) atomicAdd(&lh[ei[E + i] >> 8], 1);
    __syncthreads();
    lcur[t] = lh[t] ? atomicAdd(&bcursor[t], lh[t]) : 0;
    __syncthreads();
    for (int i = lo + t; i < hi; i += 256) {
        int d = ei[E + i];
        int p = atomicAdd(&lcur[d >> 8], 1);
        rec_tmp[p] = ((uint_t)ei[i] << 16) | f2bf_rne(ewt[i]);
        dlo_tmp[p] = (uchar_t)(d & 255);
    }
}

// S4: within-bucket counting sort by dst&255 (all in LDS); emit row_ptr+erec.
__global__ void __launch_bounds__(256) bsort_kernel(
        const uint_t* __restrict__ rec_tmp, const uchar_t* __restrict__ dlo_tmp,
        const int* __restrict__ bucket_base, int* __restrict__ row_ptr,
        uint_t* __restrict__ erec, int N, int E) {
    __shared__ int hist[256];
    __shared__ int scn[256];
    __shared__ int cur[256];
    int b = blockIdx.x, t = threadIdx.x;
    int lo = bucket_base[b], hi = bucket_base[b + 1];
    hist[t] = 0;
    __syncthreads();
    for (int i = lo + t; i < hi; i += 256) atomicAdd(&hist[dlo_tmp[i]], 1);
    __syncthreads();
    int v = hist[t];
    scn[t] = v;
    __syncthreads();
    for (int off = 1; off < 256; off <<= 1) {
        int u = (t >= off) ? scn[t - off] : 0;
        __syncthreads();
        scn[t] += u;
        __syncthreads();
    }
    int excl = lo + scn[t] - v;
    int node = (b << 8) + t;
    if (node < N) row_ptr[node] = excl;
    if (b == 0 && t == 0) row_ptr[N] = E;
    cur[t] = excl;
    __syncthreads();
    for (int i = lo + t; i < hi; i += 256) {
        int p = atomicAdd(&cur[dlo_tmp[i]], 1);
        erec[p] = rec_tmp[i];
    }
}

// ---------------------------------------------------------------------------
// 4) APPNP step (bf16 rows): wave per dst node; 4 groups x 16 lanes; each
//    group owns one edge, reads the 256B bf16 row as one uint4 per lane.
//    8x unroll + 8-record prefetch; tail slots clamp to record 0
//    (src=0, w=+0.0bf): cache-broadcast hits, ~free. pk_fma f32 accumulate,
//    bf16-RNE out. h-row load hoisted.
//    ESTABLISHED FLOOR ~49 us/step: dur == FETCH/3.47 TB/s across ALL
//    variants — VALU cut (R10), trip-balance (R6), node-pair pipe (R11),
//    single-node pipe (R12), dim-slice (R13) all null or regressed.
//    Beyond-L2-fetch-bound: 12.8 MB random working set vs 4 MB/XCD L2.
// ---------------------------------------------------------------------------
__global__ void __launch_bounds__(256) prop_kernel(
        const ushort_t* __restrict__ xs, ushort_t* __restrict__ xd,
        const ushort_t* __restrict__ h, const int* __restrict__ row_ptr,
        const uint_t* __restrict__ erec, int N) {
    int wid = threadIdx.x >> 6, lane = threadIdx.x & 63;
    int node = blockIdx.x * 4 + wid;
    if (node >= N) return;
    int rs = row_ptr[node], re = row_ptr[node + 1];
    int grp = lane >> 4;        // edge slot 0..3
    int sub = lane & 15;        // dim slot: bf16 elems sub*8 .. sub*8+7

    // hoisted teleport-row load: latency hides under the edge loop
    uint4 hv = make_uint4(0u, 0u, 0u, 0u);
    if (grp == 0) hv = ((const uint4*)(h + (size_t)node * HD))[sub];

    vf2 acc2[4];
    #pragma unroll
    for (int i = 0; i < 4; i++) acc2[i] = (vf2)0.f;

    uint_t p[8];
    #pragma unroll
    for (int u = 0; u < 8; u++) {
        int e = rs + grp + 4 * u;
        p[u] = (e < re) ? erec[e] : 0u;      // src=0, w=+0.0bf
    }

    for (int base = rs; base < re; base += 32) {
        // prefetch next iteration's edge records
        uint_t q[8];
        #pragma unroll
        for (int u = 0; u < 8; u++) {
            int e = base + 32 + grp + 4 * u;
            q[u] = (e < re) ? erec[e] : 0u;
        }
        // 8 independent row gathers in flight (tail slots hit row 0, w=0)
        #pragma unroll
        for (int u = 0; u < 8; u++) {
            int   s = (int)(p[u] >> 16);
            float w = __uint_as_float(p[u] << 16);   // bf16 weight, 1 op
            vf2 w2; w2.x = w; w2.y = w;
            uint4 a = ((const uint4*)(xs + (size_t)s * HD))[sub];
            vf2 x0; x0.x = bf_lo(a.x); x0.y = bf_hi(a.x);
            vf2 x1; x1.x = bf_lo(a.y); x1.y = bf_hi(a.y);
            vf2 x2; x2.x = bf_lo(a.z); x2.y = bf_hi(a.z);
            vf2 x3; x3.x = bf_lo(a.w); x3.y = bf_hi(a.w);
            acc2[0] = pk_fma(w2, x0, acc2[0]);
            acc2[1] = pk_fma(w2, x1, acc2[1]);
            acc2[2] = pk_fma(w2, x2, acc2[2]);
            acc2[3] = pk_fma(w2, x3, acc2[3]);
        }
        #pragma unroll
        for (int u = 0; u < 8; u++) p[u] = q[u];
    }

    float acc[8];
    #pragma unroll
    for (int i = 0; i < 4; i++) { acc[2 * i] = acc2[i].x; acc[2 * i + 1] = acc2[i].y; }

    // reduce across the 4 edge groups
    #pragma unroll
    for (int off = 32; off >= 16; off >>= 1) {
        #pragma unroll
        for (int i = 0; i < 8; i++) acc[i] += __shfl_down(acc[i], off);
    }

    if (grp == 0) {
        float o[8];
        o[0] = 0.9f * acc[0] + 0.1f * bf_lo(hv.x);
        o[1] = 0.9f * acc[1] + 0.1f * bf_hi(hv.x);
        o[2] = 0.9f * acc[2] + 0.1f * bf_lo(hv.y);
        o[3] = 0.9f * acc[3] + 0.1f * bf_hi(hv.y);
        o[4] = 0.9f * acc[4] + 0.1f * bf_lo(hv.z);
        o[5] = 0.9f * acc[5] + 0.1f * bf_hi(hv.z);
        o[6] = 0.9f * acc[6] + 0.1f * bf_lo(hv.w);
        o[7] = 0.9f * acc[7] + 0.1f * bf_hi(hv.w);
        uint4 ov;
        ov.x = pack_bf2(o[0], o[1]);
        ov.y = pack_bf2(o[2], o[3]);
        ov.z = pack_bf2(o[4], o[5]);
        ov.w = pack_bf2(o[6], o[7]);
        ((uint4*)(xd + (size_t)node * HD))[sub] = ov;
    }
}

// ---------------------------------------------------------------------------
// 5) Pool: batch is sorted -> running accumulator, atomic only on boundary.
// ---------------------------------------------------------------------------
#define POOL_CHUNK 128
__global__ void pool_kernel(const ushort_t* __restrict__ x, const int* __restrict__ batch,
                            float* __restrict__ pooled, int N) {
    int j = threadIdx.x;
    int n0 = blockIdx.x * POOL_CHUNK;
    if (n0 >= N) return;
    int n1 = min(n0 + POOL_CHUNK, N);
    int cur = batch[n0];
    float acc = 0.f;
    for (int n = n0; n < n1; n++) {
        int g = batch[n];
        if (g != cur) {
            atomicAdd(&pooled[cur * HD + j], acc);
            acc = 0.f; cur = g;
        }
        acc += __uint_as_float(((uint_t)x[(size_t)n * HD + j]) << 16);
    }
    atomicAdd(&pooled[cur * HD + j], acc);
}

// ---------------------------------------------------------------------------
// 6) Head: y = log_softmax(relu(pooled@V0w+V0b) @ V1w + V1b). Block per graph.
// ---------------------------------------------------------------------------
__global__ void head_kernel(const float* __restrict__ pooled, const float* __restrict__ V0w,
                            const float* __restrict__ V0b, const float* __restrict__ V1w,
                            const float* __restrict__ V1b, float* __restrict__ out) {
    __shared__ float prow[HD];
    __shared__ float y1[HD];
    __shared__ float y2[OUTD];
    __shared__ float lse;
    int g = blockIdx.x, j = threadIdx.x;
    prow[j] = pooled[g * HD + j];
    __syncthreads();
    float a = V0b[j];
    for (int d = 0; d < HD; d++) a += prow[d] * V0w[d * HD + j];
    y1[j] = a > 0.f ? a : 0.f;
    __syncthreads();
    if (j < OUTD) {
        float a2 = V1b[j];
        for (int t = 0; t < HD; t++) a2 += y1[t] * V1w[t * OUTD + j];
        y2[j] = a2;
    }
    __syncthreads();
    if (j == 0) {
        float m = y2[0];
        for (int o = 1; o < OUTD; o++) m = fmaxf(m, y2[o]);
        float s = 0.f;
        for (int o = 0; o < OUTD; o++) s += expf(y2[o] - m);
        lse = m + logf(s);
    }
    __syncthreads();
    if (j < OUTD) out[g * OUTD + j] = y2[j] - lse;
}

// ---------------------------------------------------------------------------
extern "C" void kernel_launch(void* const* d_in, const int* in_sizes, int n_in,
                              void* d_out, int out_size, void* d_ws, size_t ws_size,
                              hipStream_t stream) {
    const float* feat = (const float*)d_in[0];
    const float* ewt  = (const float*)d_in[1];
    const float* W1   = (const float*)d_in[2];
    const float* b1   = (const float*)d_in[3];
    const float* W2   = (const float*)d_in[4];
    const float* b2   = (const float*)d_in[5];
    const float* V0w  = (const float*)d_in[6];
    const float* V0b  = (const float*)d_in[7];
    const float* V1w  = (const float*)d_in[8];
    const float* V1b  = (const float*)d_in[9];
    const int*   ei   = (const int*)d_in[10];
    const int*   batch= (const int*)d_in[11];
    const int E = in_sizes[1];
    const int N = in_sizes[11];
    float* out = (float*)d_out;

    char* ws = (char*)d_ws;
    size_t off = 0;
    auto alloc = [&](size_t bytes) -> char* {
        char* p = ws + off;
        off = (off + bytes + 255) & ~(size_t)255;
        return p;
    };
    float*    Wc        = (float*)alloc((size_t)HD * HD * 4);
    float*    bc        = (float*)alloc((size_t)HD * 4);
    ushort_t* hb        = (ushort_t*)alloc((size_t)N * HD * 2);
    ushort_t* xA        = (ushort_t*)alloc((size_t)N * HD * 2);
    ushort_t* xB        = (ushort_t*)alloc((size_t)N * HD * 2);
    float*    pooled    = (float*)alloc((size_t)NG * HD * 4);
    int*      row_ptr   = (int*)alloc((size_t)(N + 1) * 4);
    int*      gbhist    = (int*)alloc((size_t)256 * 4);
    int*      bucket_b  = (int*)alloc((size_t)257 * 4);
    int*      bcursor   = (int*)alloc((size_t)256 * 4);
    uint_t*   rec_tmp   = (uint_t*)alloc((size_t)E * 4);
    uchar_t*  dlo_tmp   = (uchar_t*)alloc((size_t)E);
    uint_t*   erec      = (uint_t*)alloc((size_t)E * 4);
    (void)ws_size;

    hipMemsetAsync(gbhist, 0, (size_t)256 * 4, stream);
    hipMemsetAsync(pooled, 0, (size_t)NG * HD * 4, stream);

    const int NBK    = (N + 255) >> 8;          // dst buckets (<=256 for N<65536)
    const int SBLK   = 256;                     // edge scatter blocks
    const int chunk  = (E + SBLK - 1) / SBLK;   // edges per scatter block

    wc_kernel<<<64, 256, 0, stream>>>(W1, b1, W2, b2, Wc, bc);
    feat_kernel<<<(N + FNT - 1) / FNT, 256, 0, stream>>>(feat, Wc, bc, hb, N);
    bcount_kernel<<<SBLK, 256, 0, stream>>>(ei, gbhist, E, chunk);
    bscan_kernel<<<1, 256, 0, stream>>>(gbhist, bucket_b, bcursor, NBK, E);
    bscatter_kernel<<<SBLK, 256, 0, stream>>>(ei, ewt, bcursor, rec_tmp, dlo_tmp, E, chunk);
    bsort_kernel<<<NBK, 256, 0, stream>>>(rec_tmp, dlo_tmp, bucket_b, row_ptr, erec, N, E);

    const ushort_t* src = hb;
    ushort_t* dst = xA;
    for (int k = 0; k < KSTEPS; k++) {
        prop_kernel<<<(N + 3) / 4, 256, 0, stream>>>(src, dst, hb, row_ptr, erec, N);
        src = dst;
        dst = (dst == xA) ? xB : xA;
    }

    pool_kernel<<<(N + POOL_CHUNK - 1) / POOL_CHUNK, HD, 0, stream>>>(src, batch, pooled, N);
    head_kernel<<<NG, HD, 0, stream>>>(pooled, V0w, V0b, V1w, V1b, out);
}

// Round 16
// 726.542 us; speedup vs baseline: 1.0226x; 1.0226x over previous
//
#include <hip/hip_runtime.h>
#include <hip/hip_fp16.h>
#include <cstdint>

#define HD    128
#define OUTD  10
#define NG    512
#define KSTEPS 10

typedef unsigned short ushort_t;
typedef unsigned int   uint_t;
typedef unsigned char  uchar_t;
typedef float vf2 __attribute__((ext_vector_type(2)));
typedef short bf16x8 __attribute__((ext_vector_type(8)));   // MFMA A/B frag (8 bf16)
typedef float f32x4  __attribute__((ext_vector_type(4)));   // MFMA C/D frag

// bf16 helpers (x/h stored as bf16: REQUIRED — propagated values reach ~1e10,
// f16 overflows at 65504 (R9 failure). f32 accumulate everywhere.
// fp8 x-storage is dead too: current absmax err 1.72e10 vs threshold 5.29e10,
// fp8 adds ~15x storage rounding -> would blow threshold.)
__device__ __forceinline__ float bf_lo(uint_t u) { return __uint_as_float(u << 16); }
__device__ __forceinline__ float bf_hi(uint_t u) { return __uint_as_float(u & 0xFFFF0000u); }
__device__ __forceinline__ uint_t f2bf_rne(float f) {          // 16-bit result
    uint_t u = __float_as_uint(f);
    return (u + 0x7FFFu + ((u >> 16) & 1u)) >> 16;
}
__device__ __forceinline__ uint_t pack_bf2(float lo, float hi) {
    return f2bf_rne(lo) | (f2bf_rne(hi) << 16);
}

// packed f32 FMA (CDNA VOP3P): d = a*b + c on both lanes of the pair.
__device__ __forceinline__ vf2 pk_fma(vf2 a, vf2 b, vf2 c) {
    vf2 d;
    asm("v_pk_fma_f32 %0, %1, %2, %3" : "=v"(d) : "v"(a), "v"(b), "v"(c));
    return d;
}

// ---------------------------------------------------------------------------
// 1) Collapse the two linear layers: Wc = W1@W2, bc = b1@W2 + b2.
//    Also emit Wcb: bf16 Wc pre-TRANSPOSED to [j][d] so feat's B-staging is
//    a pure vectorized copy (R15 lesson: MFMA feat was staging-bound).
// ---------------------------------------------------------------------------
__global__ void wc_kernel(const float* __restrict__ W1, const float* __restrict__ b1,
                          const float* __restrict__ W2, const float* __restrict__ b2,
                          float* __restrict__ Wc, ushort_t* __restrict__ Wcb,
                          float* __restrict__ bc) {
    int idx = blockIdx.x * 256 + threadIdx.x;      // 0..16383
    int d = idx >> 7, j = idx & 127;
    float s = 0.f;
    for (int t = 0; t < HD; t++) s += W1[d * HD + t] * W2[t * HD + j];
    Wc[idx] = s;
    Wcb[j * HD + d] = (ushort_t)f2bf_rne(s);       // [j][d] bf16
    if (idx < HD) {
        float sb = b2[idx];
        for (int t = 0; t < HD; t++) sb += b1[t] * W2[t * HD + idx];
        bc[idx] = sb;
    }
}

// ---------------------------------------------------------------------------
// 2) h[n][j] = sum_d feat[d][n]*Wc[d][j] + bc[j] -> bf16 [N][128]
//    MFMA 16x16x32_bf16, 64 nodes x 128 j per block, 4 waves.
//    R16: staging vectorized (was 96 scalar iters -> 16): B = 8 uint4 copies
//    of pre-transposed bf16 Wcb; A = 8 float4-over-n loads + 4 scalar LDS
//    writes each (the [d][n]->[n][d] transpose forces scalar writes; write
//    count unchanged). Fragment mapping (m89/m91-verified, R15 refcheck'd):
//    A row=lane&15, k=(lane>>4)*8+i; B col=lane&15; D col=lane&15,
//    row=(lane>>4)*4+reg. LDS rows padded to 136 ushorts.
// ---------------------------------------------------------------------------
#define FNT 64                  // nodes per block
__global__ void __launch_bounds__(256) feat_kernel(
        const float* __restrict__ feat, const ushort_t* __restrict__ Wcb,
        const float* __restrict__ bc, ushort_t* __restrict__ h, int N) {
    __shared__ ushort_t As[FNT][136];         // [node][d] bf16, 17.4 KB
    __shared__ ushort_t Bt[HD][136];          // [j][d]    bf16, 34.8 KB
    int t = threadIdx.x;
    int nb0 = blockIdx.x * FNT;
    int wid = t >> 6, lane = t & 63;

    // stage B: Wcb[j][d] -> Bt[j][d], 32 KB as uint4 (8 iters, coalesced)
    #pragma unroll
    for (int k = 0; k < (HD * HD * 2) / (256 * 16); k++) {   // 8 iters
        int l = k * 256 + t;
        int j = l >> 4, seg = l & 15;
        *(uint4*)&Bt[j][seg * 8] = *(const uint4*)(Wcb + j * HD + seg * 8);
    }
    // stage A: feat[d][nb0..+63] -> bf16 As[n][d], float4 over n (8 iters)
    if (nb0 + FNT <= N) {
        #pragma unroll
        for (int k = 0; k < (FNT * HD) / (256 * 4); k++) {   // 8 iters
            int l = k * 256 + t;
            int d = l >> 4, n4 = (l & 15) * 4;
            float4 v = *(const float4*)(feat + (size_t)d * N + nb0 + n4);
            As[n4 + 0][d] = (ushort_t)f2bf_rne(v.x);
            As[n4 + 1][d] = (ushort_t)f2bf_rne(v.y);
            As[n4 + 2][d] = (ushort_t)f2bf_rne(v.z);
            As[n4 + 3][d] = (ushort_t)f2bf_rne(v.w);
        }
    } else {
        #pragma unroll
        for (int k = 0; k < (FNT * HD) / 256; k++) {         // guarded tail
            int l = k * 256 + t;
            int n = l & 63, d = l >> 6;
            int nn = nb0 + n;
            float v = (nn < N) ? feat[(size_t)d * N + nn] : 0.f;
            As[n][d] = (ushort_t)f2bf_rne(v);
        }
    }
    __syncthreads();

    int arow = wid * 16 + (lane & 15);        // node row within block
    int koff = (lane >> 4) * 8;               // k-offset within 32-chunk

    f32x4 acc[8];
    #pragma unroll
    for (int jt = 0; jt < 8; jt++) acc[jt] = (f32x4)0.f;

    #pragma unroll
    for (int ks = 0; ks < 4; ks++) {          // K = 128 in 4 chunks of 32
        bf16x8 av = *(const bf16x8*)&As[arow][ks * 32 + koff];
        #pragma unroll
        for (int jt = 0; jt < 8; jt++) {
            bf16x8 bv = *(const bf16x8*)&Bt[jt * 16 + (lane & 15)][ks * 32 + koff];
            acc[jt] = __builtin_amdgcn_mfma_f32_16x16x32_bf16(av, bv, acc[jt], 0, 0, 0);
        }
    }

    // epilogue: D col=lane&15 (j within tile), row=(lane>>4)*4+r (node)
    int drow = wid * 16 + (lane >> 4) * 4;    // node row base for this lane
    #pragma unroll
    for (int jt = 0; jt < 8; jt++) {
        int j = jt * 16 + (lane & 15);
        float bb = bc[j];
        #pragma unroll
        for (int r = 0; r < 4; r++) {
            int n = nb0 + drow + r;
            if (n < N) h[(size_t)n * HD + j] = (ushort_t)f2bf_rne(acc[jt][r] + bb);
        }
    }
}

// ---------------------------------------------------------------------------
// 3) CSR build via two-level bucket sort (NO global per-node atomics).
// ---------------------------------------------------------------------------

// S1: global bucket sizes (LDS hist, then one atomic per nonzero bucket/block)
__global__ void __launch_bounds__(256) bcount_kernel(
        const int* __restrict__ ei, int* __restrict__ gbhist, int E, int chunk) {
    __shared__ int lh[256];
    int b = blockIdx.x, t = threadIdx.x;
    lh[t] = 0;
    __syncthreads();
    int lo = b * chunk, hi = min(E, lo + chunk);
    for (int i = lo + t; i < hi; i += 256) atomicAdd(&lh[ei[E + i] >> 8], 1);
    __syncthreads();
    if (lh[t]) atomicAdd(&gbhist[t], lh[t]);
}

// S2: exclusive scan of bucket sizes -> bucket_base[0..NBK], bcursor init
__global__ void bscan_kernel(const int* __restrict__ gbhist, int* __restrict__ bucket_base,
                             int* __restrict__ bcursor, int NBK, int E) {
    __shared__ int sm[256];
    int t = threadIdx.x;
    int v = (t < NBK) ? gbhist[t] : 0;
    sm[t] = v;
    __syncthreads();
    for (int off = 1; off < 256; off <<= 1) {
        int u = (t >= off) ? sm[t - off] : 0;
        __syncthreads();
        sm[t] += u;
        __syncthreads();
    }
    int excl = sm[t] - v;
    if (t < NBK) { bucket_base[t] = excl; bcursor[t] = excl; }
    if (t == 0) bucket_base[NBK] = E;
}

// S3: scatter edges into bucket-ordered intermediate (rec + low-byte of dst).
// Record: (src << 16) | bf16(weight) — bf16 w decodes with ONE shift in prop.
__global__ void __launch_bounds__(256) bscatter_kernel(
        const int* __restrict__ ei, const float* __restrict__ ewt,
        int* __restrict__ bcursor, uint_t* __restrict__ rec_tmp,
        uchar_t* __restrict__ dlo_tmp, int E, int chunk) {
    __shared__ int lh[256];
    __shared__ int lcur[256];
    int b = blockIdx.x, t = threadIdx.x;
    lh[t] = 0;
    __syncthreads();
    int lo = b * chunk, hi = min(E, lo + chunk);
    for (int i = lo + t; i < hi; i += 256) atomicAdd(&lh[ei[E + i] >> 8], 1);
    __syncthreads();
    lcur[t] = lh[t] ? atomicAdd(&bcursor[t], lh[t]) : 0;
    __syncthreads();
    for (int i = lo + t; i < hi; i += 256) {
        int d = ei[E + i];
        int p = atomicAdd(&lcur[d >> 8], 1);
        rec_tmp[p] = ((uint_t)ei[i] << 16) | f2bf_rne(ewt[i]);
        dlo_tmp[p] = (uchar_t)(d & 255);
    }
}

// S4: within-bucket counting sort by dst&255 (all in LDS); emit row_ptr+erec.
__global__ void __launch_bounds__(256) bsort_kernel(
        const uint_t* __restrict__ rec_tmp, const uchar_t* __restrict__ dlo_tmp,
        const int* __restrict__ bucket_base, int* __restrict__ row_ptr,
        uint_t* __restrict__ erec, int N, int E) {
    __shared__ int hist[256];
    __shared__ int scn[256];
    __shared__ int cur[256];
    int b = blockIdx.x, t = threadIdx.x;
    int lo = bucket_base[b], hi = bucket_base[b + 1];
    hist[t] = 0;
    __syncthreads();
    for (int i = lo + t; i < hi; i += 256) atomicAdd(&hist[dlo_tmp[i]], 1);
    __syncthreads();
    int v = hist[t];
    scn[t] = v;
    __syncthreads();
    for (int off = 1; off < 256; off <<= 1) {
        int u = (t >= off) ? scn[t - off] : 0;
        __syncthreads();
        scn[t] += u;
        __syncthreads();
    }
    int excl = lo + scn[t] - v;
    int node = (b << 8) + t;
    if (node < N) row_ptr[node] = excl;
    if (b == 0 && t == 0) row_ptr[N] = E;
    cur[t] = excl;
    __syncthreads();
    for (int i = lo + t; i < hi; i += 256) {
        int p = atomicAdd(&cur[dlo_tmp[i]], 1);
        erec[p] = rec_tmp[i];
    }
}

// ---------------------------------------------------------------------------
// 4) APPNP step (bf16 rows): wave per dst node; 4 groups x 16 lanes; each
//    group owns one edge, reads the 256B bf16 row as one uint4 per lane.
//    8x unroll + 8-record prefetch; tail slots clamp to record 0
//    (src=0, w=+0.0bf): cache-broadcast hits, ~free. pk_fma f32 accumulate,
//    bf16-RNE out. h-row load hoisted.
//    ESTABLISHED FLOOR ~49.4 us/step: dur == FETCH/3.47 TB/s across ALL
//    variants (7-for-7) — VALU cut (R10), trip-balance (R6), node-pair pipe
//    (R11), single-node pipe (R12), dim-slice (R13) null or regressed.
//    Beyond-L2-fetch-bound: 12.8 MB random working set vs 4 MB/XCD L2;
//    random graph -> no reorder-locality; fp8 precision-dead (see top).
// ---------------------------------------------------------------------------
__global__ void __launch_bounds__(256) prop_kernel(
        const ushort_t* __restrict__ xs, ushort_t* __restrict__ xd,
        const ushort_t* __restrict__ h, const int* __restrict__ row_ptr,
        const uint_t* __restrict__ erec, int N) {
    int wid = threadIdx.x >> 6, lane = threadIdx.x & 63;
    int node = blockIdx.x * 4 + wid;
    if (node >= N) return;
    int rs = row_ptr[node], re = row_ptr[node + 1];
    int grp = lane >> 4;        // edge slot 0..3
    int sub = lane & 15;        // dim slot: bf16 elems sub*8 .. sub*8+7

    // hoisted teleport-row load: latency hides under the edge loop
    uint4 hv = make_uint4(0u, 0u, 0u, 0u);
    if (grp == 0) hv = ((const uint4*)(h + (size_t)node * HD))[sub];

    vf2 acc2[4];
    #pragma unroll
    for (int i = 0; i < 4; i++) acc2[i] = (vf2)0.f;

    uint_t p[8];
    #pragma unroll
    for (int u = 0; u < 8; u++) {
        int e = rs + grp + 4 * u;
        p[u] = (e < re) ? erec[e] : 0u;      // src=0, w=+0.0bf
    }

    for (int base = rs; base < re; base += 32) {
        // prefetch next iteration's edge records
        uint_t q[8];
        #pragma unroll
        for (int u = 0; u < 8; u++) {
            int e = base + 32 + grp + 4 * u;
            q[u] = (e < re) ? erec[e] : 0u;
        }
        // 8 independent row gathers in flight (tail slots hit row 0, w=0)
        #pragma unroll
        for (int u = 0; u < 8; u++) {
            int   s = (int)(p[u] >> 16);
            float w = __uint_as_float(p[u] << 16);   // bf16 weight, 1 op
            vf2 w2; w2.x = w; w2.y = w;
            uint4 a = ((const uint4*)(xs + (size_t)s * HD))[sub];
            vf2 x0; x0.x = bf_lo(a.x); x0.y = bf_hi(a.x);
            vf2 x1; x1.x = bf_lo(a.y); x1.y = bf_hi(a.y);
            vf2 x2; x2.x = bf_lo(a.z); x2.y = bf_hi(a.z);
            vf2 x3; x3.x = bf_lo(a.w); x3.y = bf_hi(a.w);
            acc2[0] = pk_fma(w2, x0, acc2[0]);
            acc2[1] = pk_fma(w2, x1, acc2[1]);
            acc2[2] = pk_fma(w2, x2, acc2[2]);
            acc2[3] = pk_fma(w2, x3, acc2[3]);
        }
        #pragma unroll
        for (int u = 0; u < 8; u++) p[u] = q[u];
    }

    float acc[8];
    #pragma unroll
    for (int i = 0; i < 4; i++) { acc[2 * i] = acc2[i].x; acc[2 * i + 1] = acc2[i].y; }

    // reduce across the 4 edge groups
    #pragma unroll
    for (int off = 32; off >= 16; off >>= 1) {
        #pragma unroll
        for (int i = 0; i < 8; i++) acc[i] += __shfl_down(acc[i], off);
    }

    if (grp == 0) {
        float o[8];
        o[0] = 0.9f * acc[0] + 0.1f * bf_lo(hv.x);
        o[1] = 0.9f * acc[1] + 0.1f * bf_hi(hv.x);
        o[2] = 0.9f * acc[2] + 0.1f * bf_lo(hv.y);
        o[3] = 0.9f * acc[3] + 0.1f * bf_hi(hv.y);
        o[4] = 0.9f * acc[4] + 0.1f * bf_lo(hv.z);
        o[5] = 0.9f * acc[5] + 0.1f * bf_hi(hv.z);
        o[6] = 0.9f * acc[6] + 0.1f * bf_lo(hv.w);
        o[7] = 0.9f * acc[7] + 0.1f * bf_hi(hv.w);
        uint4 ov;
        ov.x = pack_bf2(o[0], o[1]);
        ov.y = pack_bf2(o[2], o[3]);
        ov.z = pack_bf2(o[4], o[5]);
        ov.w = pack_bf2(o[6], o[7]);
        ((uint4*)(xd + (size_t)node * HD))[sub] = ov;
    }
}

// ---------------------------------------------------------------------------
// 5) Pool: batch is sorted -> running accumulator, atomic only on boundary.
// ---------------------------------------------------------------------------
#define POOL_CHUNK 128
__global__ void pool_kernel(const ushort_t* __restrict__ x, const int* __restrict__ batch,
                            float* __restrict__ pooled, int N) {
    int j = threadIdx.x;
    int n0 = blockIdx.x * POOL_CHUNK;
    if (n0 >= N) return;
    int n1 = min(n0 + POOL_CHUNK, N);
    int cur = batch[n0];
    float acc = 0.f;
    for (int n = n0; n < n1; n++) {
        int g = batch[n];
        if (g != cur) {
            atomicAdd(&pooled[cur * HD + j], acc);
            acc = 0.f; cur = g;
        }
        acc += __uint_as_float(((uint_t)x[(size_t)n * HD + j]) << 16);
    }
    atomicAdd(&pooled[cur * HD + j], acc);
}

// ---------------------------------------------------------------------------
// 6) Head: y = log_softmax(relu(pooled@V0w+V0b) @ V1w + V1b). Block per graph.
// ---------------------------------------------------------------------------
__global__ void head_kernel(const float* __restrict__ pooled, const float* __restrict__ V0w,
                            const float* __restrict__ V0b, const float* __restrict__ V1w,
                            const float* __restrict__ V1b, float* __restrict__ out) {
    __shared__ float prow[HD];
    __shared__ float y1[HD];
    __shared__ float y2[OUTD];
    __shared__ float lse;
    int g = blockIdx.x, j = threadIdx.x;
    prow[j] = pooled[g * HD + j];
    __syncthreads();
    float a = V0b[j];
    for (int d = 0; d < HD; d++) a += prow[d] * V0w[d * HD + j];
    y1[j] = a > 0.f ? a : 0.f;
    __syncthreads();
    if (j < OUTD) {
        float a2 = V1b[j];
        for (int t = 0; t < HD; t++) a2 += y1[t] * V1w[t * OUTD + j];
        y2[j] = a2;
    }
    __syncthreads();
    if (j == 0) {
        float m = y2[0];
        for (int o = 1; o < OUTD; o++) m = fmaxf(m, y2[o]);
        float s = 0.f;
        for (int o = 0; o < OUTD; o++) s += expf(y2[o] - m);
        lse = m + logf(s);
    }
    __syncthreads();
    if (j < OUTD) out[g * OUTD + j] = y2[j] - lse;
}

// ---------------------------------------------------------------------------
extern "C" void kernel_launch(void* const* d_in, const int* in_sizes, int n_in,
                              void* d_out, int out_size, void* d_ws, size_t ws_size,
                              hipStream_t stream) {
    const float* feat = (const float*)d_in[0];
    const float* ewt  = (const float*)d_in[1];
    const float* W1   = (const float*)d_in[2];
    const float* b1   = (const float*)d_in[3];
    const float* W2   = (const float*)d_in[4];
    const float* b2   = (const float*)d_in[5];
    const float* V0w  = (const float*)d_in[6];
    const float* V0b  = (const float*)d_in[7];
    const float* V1w  = (const float*)d_in[8];
    const float* V1b  = (const float*)d_in[9];
    const int*   ei   = (const int*)d_in[10];
    const int*   batch= (const int*)d_in[11];
    const int E = in_sizes[1];
    const int N = in_sizes[11];
    float* out = (float*)d_out;

    char* ws = (char*)d_ws;
    size_t off = 0;
    auto alloc = [&](size_t bytes) -> char* {
        char* p = ws + off;
        off = (off + bytes + 255) & ~(size_t)255;
        return p;
    };
    float*    Wc        = (float*)alloc((size_t)HD * HD * 4);
    ushort_t* Wcb       = (ushort_t*)alloc((size_t)HD * HD * 2);
    float*    bc        = (float*)alloc((size_t)HD * 4);
    ushort_t* hb        = (ushort_t*)alloc((size_t)N * HD * 2);
    ushort_t* xA        = (ushort_t*)alloc((size_t)N * HD * 2);
    ushort_t* xB        = (ushort_t*)alloc((size_t)N * HD * 2);
    float*    pooled    = (float*)alloc((size_t)NG * HD * 4);
    int*      row_ptr   = (int*)alloc((size_t)(N + 1) * 4);
    int*      gbhist    = (int*)alloc((size_t)256 * 4);
    int*      bucket_b  = (int*)alloc((size_t)257 * 4);
    int*      bcursor   = (int*)alloc((size_t)256 * 4);
    uint_t*   rec_tmp   = (uint_t*)alloc((size_t)E * 4);
    uchar_t*  dlo_tmp   = (uchar_t*)alloc((size_t)E);
    uint_t*   erec      = (uint_t*)alloc((size_t)E * 4);
    (void)ws_size;

    hipMemsetAsync(gbhist, 0, (size_t)256 * 4, stream);
    hipMemsetAsync(pooled, 0, (size_t)NG * HD * 4, stream);

    const int NBK    = (N + 255) >> 8;          // dst buckets (<=256 for N<65536)
    const int SBLK   = 256;                     // edge scatter blocks
    const int chunk  = (E + SBLK - 1) / SBLK;   // edges per scatter block

    wc_kernel<<<64, 256, 0, stream>>>(W1, b1, W2, b2, Wc, Wcb, bc);
    feat_kernel<<<(N + FNT - 1) / FNT, 256, 0, stream>>>(feat, Wcb, bc, hb, N);
    bcount_kernel<<<SBLK, 256, 0, stream>>>(ei, gbhist, E, chunk);
    bscan_kernel<<<1, 256, 0, stream>>>(gbhist, bucket_b, bcursor, NBK, E);
    bscatter_kernel<<<SBLK, 256, 0, stream>>>(ei, ewt, bcursor, rec_tmp, dlo_tmp, E, chunk);
    bsort_kernel<<<NBK, 256, 0, stream>>>(rec_tmp, dlo_tmp, bucket_b, row_ptr, erec, N, E);

    const ushort_t* src = hb;
    ushort_t* dst = xA;
    for (int k = 0; k < KSTEPS; k++) {
        prop_kernel<<<(N + 3) / 4, 256, 0, stream>>>(src, dst, hb, row_ptr, erec, N);
        src = dst;
        dst = (dst == xA) ? xB : xA;
    }

    pool_kernel<<<(N + POOL_CHUNK - 1) / POOL_CHUNK, HD, 0, stream>>>(src, batch, pooled, N);
    head_kernel<<<NG, HD, 0, stream>>>(pooled, V0w, V0b, V1w, V1b, out);
}